// Round 8
// baseline (589.449 us; speedup 1.0000x reference)
//
#include <hip/hip_runtime.h>

// WaveInputEncoder on MI355X — round 8.
// vs r7: GEMMs switched from mfma_f32_16x16x32_bf16 to mfma_f32_32x32x16_bf16
// (−17% matrix-pipe cycles, half the MFMA instruction count). The 4-phase
// schedule, staging macros, and vmcnt ledger carry over from r7 verbatim;
// only fragment load offsets, MFMA calls, and epilogues change.
// A/B frag: row=lane&31, k=(lane>>5)*8+j. C/D: col=lane&31,
// row=(reg&3)+8*(reg>>2)+4*(lane>>5)  [m74/m101].

typedef __attribute__((ext_vector_type(8))) short s16x8;
typedef __attribute__((ext_vector_type(4))) short s16x4;
typedef __attribute__((ext_vector_type(4))) float f32x4;
typedef __attribute__((ext_vector_type(16))) float f32x16;

#define SCHED0 __builtin_amdgcn_sched_barrier(0)
#define BARR   __builtin_amdgcn_s_barrier()
#define LGKM0  asm volatile("s_waitcnt lgkmcnt(0)" ::: "memory")
#define VM(n)  asm volatile("s_waitcnt vmcnt(" #n ")" ::: "memory")

__device__ __forceinline__ short f2bf(float x){
  unsigned u = __float_as_uint(x);
  unsigned r = (u + 0x7fffu + ((u >> 16) & 1u)) >> 16;   // RNE
  return (short)r;
}
__device__ __forceinline__ float bf2f(short x){
  return __uint_as_float(((unsigned)(unsigned short)x) << 16);
}
__device__ __forceinline__ void gload16(const void* g, void* l){
  __builtin_amdgcn_global_load_lds((const __attribute__((address_space(1))) void*)g,
                                   (__attribute__((address_space(3))) void*)l, 16, 0, 0);
}
__device__ __forceinline__ float gelu_f(float v){
  float u2 = v * (0.7978845608f + 0.0356774081f * v * v);
  float e = __expf(2.0f * u2);
  float th = 1.0f - 2.0f / (e + 1.0f);
  return 0.5f * v * (1.0f + th);
}

// ---------------- prep kernels ----------------
__global__ void prep_wcs_k(const float* __restrict__ mw, const float* __restrict__ po,
                           float* __restrict__ wcs){
  int i = threadIdx.x;
  if (i < 32){
    wcs[i]      = log1pf(expf(mw[i]));  // softplus
    wcs[32 + i] = cosf(po[i]);
    wcs[64 + i] = sinf(po[i]);
  }
}

__global__ __launch_bounds__(256) void prep_tab_k(float* __restrict__ ctab, float* __restrict__ stab){
  int idx = blockIdx.x * 256 + threadIdx.x;      // idx = m*4096 + t
  int m = idx >> 12, t = idx & 4095;
  int r = (m * t) & 4095;
  float ang = (float)r * 1.5339807878856412e-3f; // 2*pi/4096
  float s, c; sincosf(ang, &s, &c);
  ctab[idx] = c; stab[idx] = s;
}

// transpose fp32 (R x C) -> bf16 (C x R), 64x64 LDS tiles
__global__ __launch_bounds__(256) void transpose_bf16_k(const float* __restrict__ src,
                                                        short* __restrict__ dst,
                                                        int R, int C){
  __shared__ float tile[64][65];
  int c0 = blockIdx.x * 64, r0 = blockIdx.y * 64;
  for (int i = 0; i < 16; ++i){
    int idx = i * 256 + threadIdx.x;
    int rr = idx >> 6, cc = idx & 63;
    tile[rr][cc] = src[(size_t)(r0 + rr) * C + c0 + cc];
  }
  __syncthreads();
  for (int i = 0; i < 16; ++i){
    int idx = i * 256 + threadIdx.x;
    int cc = idx >> 6, rr = idx & 63;
    dst[(size_t)(c0 + cc) * R + r0 + rr] = f2bf(tile[rr][cc]);
  }
}

// ---------------- kernel A ----------------
__global__ __launch_bounds__(256) void kernelA(const int* __restrict__ tokens,
    const float* __restrict__ frw, const float* __restrict__ fiw,
    const float* __restrict__ wcs, const float* __restrict__ ftew,
    const float* __restrict__ fteb, const float* __restrict__ posph,
    float* __restrict__ xout){
  __shared__ float ffs[4][64];
  __shared__ float xs[4][1024];
  __shared__ float wsh[96];
  int tid = threadIdx.x;
  int b = blockIdx.x >> 10, t0 = (blockIdx.x & 1023) * 4;
  if (tid < 96) wsh[tid] = wcs[tid];
  __syncthreads();
  if (tid < 128){
    int tk = tid >> 5, m = tid & 31;
    int tok = tokens[b * 4096 + t0 + tk];
    float w = wsh[m];
    float re = frw[(size_t)tok * 32 + m] * w;
    float im = fiw[(size_t)tok * 32 + m] * w;
    float c = wsh[32 + m], s = wsh[64 + m];
    ffs[tk][m]      = re * c - im * s;
    ffs[tk][32 + m] = re * s + im * c;
  }
  __syncthreads();
  for (int p = 0; p < 4; ++p){
    int dd = p * 256 + tid;
    float bb = fteb[dd];
    float a0 = bb, a1 = bb, a2 = bb, a3 = bb;
    #pragma unroll 8
    for (int k = 0; k < 64; ++k){
      float wv = ftew[k * 1024 + dd];
      a0 += ffs[0][k] * wv; a1 += ffs[1][k] * wv;
      a2 += ffs[2][k] * wv; a3 += ffs[3][k] * wv;
    }
    xs[0][dd] = a0; xs[1][dd] = a1; xs[2][dd] = a2; xs[3][dd] = a3;
  }
  __syncthreads();
  for (int p = 0; p < 4; ++p){
    int dd = p * 256 + tid, dm = (dd + 1023) & 1023;
    #pragma unroll
    for (int tk = 0; tk < 4; ++tk){
      float pp = posph[(size_t)(t0 + tk) * 1024 + dd];
      float p2 = pp * pp;
      float sp = pp * (1.0f - p2 * (1.0f/6.0f) + p2 * p2 * (1.0f/120.0f));
      float cp = 1.0f - p2 * 0.5f + p2 * p2 * (1.0f/24.0f);
      xout[((size_t)b * 4096 + t0 + tk) * 1024 + dd] = xs[tk][dd] * cp + xs[tk][dm] * sp;
    }
  }
}

// ---------------- kernel B: truncated forward DFT via rotation recurrence ----------------
__global__ __launch_bounds__(256) void kernelB2(const float* __restrict__ xin,
    float* __restrict__ Pr, float* __restrict__ Pi){
  __shared__ float xsh[64][32];
  int tid = threadIdx.x;
  int bx = blockIdx.x;
  int b = bx >> 8, dch = (bx >> 3) & 31, tc = bx & 7;
  int d0 = dch * 32;
  int t_start = tc * 512;
  int dg = tid >> 5, m = tid & 31;
  const float TPN = 1.5339807878856412e-3f;
  int r0 = (m * t_start) & 4095;
  float cw, sw; sincosf(-(float)r0 * TPN, &sw, &cw);
  float cs, ss; sincosf(-(float)m * TPN, &ss, &cs);
  float ar[4] = {0,0,0,0}, ai[4] = {0,0,0,0};
  for (int t0 = t_start; t0 < t_start + 512; t0 += 64){
    __syncthreads();
    #pragma unroll
    for (int i = 0; i < 2; ++i){
      int unit = i * 256 + tid;
      int tt = unit >> 3, du = (unit & 7) * 4;
      *(f32x4*)&xsh[tt][du] = *(const f32x4*)&xin[((size_t)b * 4096 + t0 + tt) * 1024 + d0 + du];
    }
    __syncthreads();
    #pragma unroll 4
    for (int tt = 0; tt < 64; ++tt){
      f32x4 xv = *(const f32x4*)&xsh[tt][dg * 4];
      #pragma unroll
      for (int j = 0; j < 4; ++j){ ar[j] += xv[j] * cw; ai[j] += xv[j] * sw; }
      float cn = cw * cs - sw * ss;
      sw = cw * ss + sw * cs; cw = cn;
    }
  }
  #pragma unroll
  for (int j = 0; j < 4; ++j){
    int d = d0 + dg * 4 + j;
    size_t idx = (((size_t)tc * 4 + b) * 1024 + d) * 32 + m;
    Pr[idx] = ar[j]; Pi[idx] = ai[j];
  }
}

__global__ __launch_bounds__(256) void reduceB_k(const float* __restrict__ Pr,
    const float* __restrict__ Pi, float* __restrict__ Xr, float* __restrict__ Xi){
  int lin = blockIdx.x * 256 + threadIdx.x;
  int m = lin & 31, d = (lin >> 5) & 1023, b = lin >> 15;
  float sr = 0.0f, si = 0.0f;
  for (int tc = 0; tc < 8; ++tc){
    size_t idx = (((size_t)tc * 4 + b) * 1024 + d) * 32 + m;
    sr += Pr[idx]; si += Pi[idx];
  }
  int n = d >> 7, jj = d & 127;
  size_t o = (((size_t)b * 8 + n) * 32 + m) * 128 + jj;
  Xr[o] = sr * 0.015625f; Xi[o] = si * 0.015625f;
}

// ---------------- kernel C ----------------
__global__ __launch_bounds__(128) void kernelC(const float* __restrict__ Xr, const float* __restrict__ Xi,
    const float* __restrict__ awr, const float* __restrict__ awi,
    float* __restrict__ Or, float* __restrict__ Oi){
  __shared__ float xr_s[4][128], xi_s[4][128];
  int nm = blockIdx.x; int n = nm >> 5, m = nm & 31;
  int i = threadIdx.x;
  for (int b = 0; b < 4; ++b){
    size_t src = (((size_t)b * 8 + n) * 32 + m) * 128 + i;
    xr_s[b][i] = Xr[src]; xi_s[b][i] = Xi[src];
  }
  __syncthreads();
  float accr[4] = {0,0,0,0}, acci[4] = {0,0,0,0};
  size_t wb = (((size_t)n * 32 + m) * 128 + i) * 128;
  for (int j = 0; j < 128; ++j){
    float wr = awr[wb + j], wi = awi[wb + j];
    #pragma unroll
    for (int b = 0; b < 4; ++b){
      accr[b] += wr * xr_s[b][j] - wi * xi_s[b][j];
      acci[b] += wr * xi_s[b][j] + wi * xr_s[b][j];
    }
  }
  #pragma unroll
  for (int b = 0; b < 4; ++b){
    float vr = accr[b], vi = acci[b];
    vr = vr > 0.01f ? vr - 0.01f : (vr < -0.01f ? vr + 0.01f : 0.0f);
    vi = vi > 0.01f ? vi - 0.01f : (vi < -0.01f ? vi + 0.01f : 0.0f);
    size_t dst = ((size_t)b * 32 + m) * 1024 + n * 128 + i;  // [b][m][d]
    Or[dst] = vr; Oi[dst] = vi;
  }
}

// ---------------- kernel D3: d-chunked irfft + residual in-place ----------------
__global__ __launch_bounds__(256) void kernelD3(const float* __restrict__ Or, const float* __restrict__ Oi,
    const float* __restrict__ ctab, const float* __restrict__ stab, float* __restrict__ y){
  __shared__ float cts[32][64], sts[32][64];
  __shared__ float Ors[32][144], Ois[32][144];
  int tid = threadIdx.x;
  int bx = blockIdx.x;
  int b = bx >> 9, tc = (bx >> 3) & 63, dc = bx & 7;
  int t0 = tc * 64, d0 = dc * 128;
  for (int i = 0; i < 8; ++i){
    int lin = i * 256 + tid;
    int m = lin >> 6, tl = lin & 63;
    float f = (m == 0 ? 1.0f : 2.0f) * 0.015625f;
    cts[m][tl] = ctab[m * 4096 + t0 + tl] * f;
    sts[m][tl] = stab[m * 4096 + t0 + tl] * f;
  }
  for (int i = 0; i < 4; ++i){
    int lin = i * 256 + tid;
    int m = lin >> 5, q = lin & 31;
    int w = q * 4;
    int ph = w + ((w >> 5) << 2);
    size_t src = ((size_t)b * 32 + m) * 1024 + d0 + w;
    *(f32x4*)&Ors[m][ph] = *(const f32x4*)&Or[src];
    *(f32x4*)&Ois[m][ph] = *(const f32x4*)&Oi[src];
  }
  __syncthreads();
  int tt = tid >> 4, dl = tid & 15;
  int wb0 = dl * 8;
  int ph0 = wb0 + ((wb0 >> 5) << 2);
  int ph1 = ph0 + 4;
  float acc[4][8];
  #pragma unroll
  for (int q = 0; q < 4; ++q)
    #pragma unroll
    for (int j = 0; j < 8; ++j) acc[q][j] = 0.f;
  for (int m = 0; m < 32; ++m){
    f32x4 cv = *(const f32x4*)&cts[m][tt * 4];
    f32x4 sv = *(const f32x4*)&sts[m][tt * 4];
    f32x4 orv0 = *(const f32x4*)&Ors[m][ph0];
    f32x4 orv1 = *(const f32x4*)&Ors[m][ph1];
    f32x4 oiv0 = *(const f32x4*)&Ois[m][ph0];
    f32x4 oiv1 = *(const f32x4*)&Ois[m][ph1];
    #pragma unroll
    for (int q = 0; q < 4; ++q){
      #pragma unroll
      for (int e = 0; e < 4; ++e){
        acc[q][e]     += cv[q] * orv0[e] - sv[q] * oiv0[e];
        acc[q][4 + e] += cv[q] * orv1[e] - sv[q] * oiv1[e];
      }
    }
  }
  #pragma unroll
  for (int q = 0; q < 4; ++q){
    size_t row = ((size_t)b * 4096 + t0 + tt * 4 + q) * 1024 + d0 + dl * 8;
    f32x4 r0 = *(const f32x4*)&y[row];
    f32x4 r1 = *(const f32x4*)&y[row + 4];
    #pragma unroll
    for (int e = 0; e < 4; ++e){ r0[e] += acc[q][e]; r1[e] += acc[q][4 + e]; }
    *(f32x4*)&y[row] = r0;
    *(f32x4*)&y[row + 4] = r1;
  }
}

// ---------------- LN1: y (f32) -> xln1 (bf16) ----------------
__global__ __launch_bounds__(256) void ln1_k(const float* __restrict__ y,
    const float* __restrict__ g, const float* __restrict__ bb, short* __restrict__ xln){
  size_t row = blockIdx.x;
  int tid = threadIdx.x;
  f32x4 v = *(const f32x4*)(y + row * 1024 + tid * 4);
  float sum = v[0] + v[1] + v[2] + v[3];
  float sq  = v[0]*v[0] + v[1]*v[1] + v[2]*v[2] + v[3]*v[3];
  for (int off = 32; off; off >>= 1){ sum += __shfl_down(sum, off); sq += __shfl_down(sq, off); }
  __shared__ float rs[4], rq[4];
  int lane = tid & 63, w = tid >> 6;
  if (lane == 0){ rs[w] = sum; rq[w] = sq; }
  __syncthreads();
  sum = rs[0] + rs[1] + rs[2] + rs[3]; sq = rq[0] + rq[1] + rq[2] + rq[3];
  float mu = sum * (1.0f / 1024.0f);
  float var = sq * (1.0f / 1024.0f) - mu * mu;
  float sc = rsqrtf(var + 1e-5f);
  s16x4 o;
  #pragma unroll
  for (int j = 0; j < 4; ++j){
    int d = tid * 4 + j;
    o[j] = f2bf((v[j] - mu) * sc * g[d] + bb[d]);
  }
  *(s16x4*)(xln + row * 1024 + tid * 4) = o;
}

// ---------------- GEMM1: 256x256, 8 waves 2Mx4N, 32x32x16 MFMA, gelu->bf16 ----------------
__global__ __launch_bounds__(512, 2) void gemm1_k(const short* __restrict__ A,
    const short* __restrict__ BT, const float* __restrict__ bias,
    short* __restrict__ Hout){
  constexpr int K = 1024, NT = 16, N = 4096;
  __shared__ __align__(16) short AsM[2 * 16384];
  __shared__ __align__(16) short BsM[2 * 16384];
  const int tid = threadIdx.x;
  const int lane = tid & 63, wv = tid >> 6;
  const int wr = wv >> 2, wc = wv & 3;          // 2M x 4N; wave = 128 rows x 64 cols
  const int l31 = lane & 31, hi = lane >> 5;
  int flat = blockIdx.x;
  int xcd = flat & 7, l = flat >> 3;
  int mb = (xcd & 3) * 8 + (l & 7);
  int nb = (xcd >> 2) * 8 + (l >> 3);
  const int arow0 = mb * 256, bcol0 = nb * 256;

  // frag LDS addressing: row R at R*64 shorts; slot for k-group g: (g ^ (R&7))*8
  const int r7m = l31 & 7;
  int kof[4];
  #pragma unroll
  for (int ks = 0; ks < 4; ++ks) kof[ks] = ((ks * 2 + hi) ^ r7m) * 8;
  const int aB = (wr * 32 + l31) * 64;          // + mf*4096 (mf*64 rows)
  const int bB = (wc * 64 + l31) * 64;          // + nf*2048 (nf*32 rows)

  const int rr = tid >> 3;
  const int sl8 = ((tid & 7) ^ (rr & 7)) * 8;
  const long aoff = (long)rr * K + sl8;
  const short* Au = A  + (long)arow0 * K;
  const short* Bu = BT + (long)bcol0 * K;
  const int ldsw = wv * 512;

#define SA1(BUF,H,T) { \
  gload16(Au + (long)((H)*128      )*K + (T)*64 + aoff, AsM + (BUF)*16384 + (H)*8192 + ldsw); \
  gload16(Au + (long)((H)*128 + 64 )*K + (T)*64 + aoff, AsM + (BUF)*16384 + (H)*8192 + 4096 + ldsw); }
#define SB1(BUF,H,T) { \
  gload16(Bu + (long)((H)*128      )*K + (T)*64 + aoff, BsM + (BUF)*16384 + (H)*8192 + ldsw); \
  gload16(Bu + (long)((H)*128 + 64 )*K + (T)*64 + aoff, BsM + (BUF)*16384 + (H)*8192 + 4096 + ldsw); }
// load A frags for half MH (mf = MH*2, MH*2+1), all 4 k-steps
#define LA32(BUF,MH) { _Pragma("unroll") for (int mf = 0; mf < 2; ++mf) \
  _Pragma("unroll") for (int ks = 0; ks < 4; ++ks) \
    af[mf][ks] = *(const s16x8*)&AsM[(BUF)*16384 + ((MH)*2+mf)*4096 + aB + kof[ks]]; }
// load B frag nf, all 4 k-steps
#define LB32(BUF,NF) { _Pragma("unroll") for (int ks = 0; ks < 4; ++ks) \
    bf[NF][ks] = *(const s16x8*)&BsM[(BUF)*16384 + (NF)*2048 + bB + kof[ks]]; }
// MFMA cluster: half MH x frag NF, 8 mfma
#define MQ1(MH,NF) { __builtin_amdgcn_s_setprio(1); \
  _Pragma("unroll") for (int mf = 0; mf < 2; ++mf) \
  _Pragma("unroll") for (int ks = 0; ks < 4; ++ks) \
    acc[(MH)*2+mf][NF] = __builtin_amdgcn_mfma_f32_32x32x16_bf16( \
        af[mf][ks], bf[NF][ks], acc[(MH)*2+mf][NF], 0, 0, 0); \
  __builtin_amdgcn_s_setprio(0); }

  f32x16 acc[4][2] = {};
  s16x8 af[2][4], bf[2][4];

  // prologue (r7 ledger): A0h0, B0h1, B0h0, A0h1, A1h0, B1h1 — VM(6)
  SA1(0,0,0); SB1(0,1,0); SB1(0,0,0); SA1(0,1,0); SA1(1,0,1); SB1(1,1,1);
  VM(6); SCHED0; BARR; SCHED0;

#define T1(T, BUF) { const bool s1 = (T)+1 < NT, s2 = (T)+2 < NT; \
  LA32(BUF,0); LB32(BUF,0); \
  if (s1) SB1(1-(BUF),0,(T)+1); \
  SCHED0; BARR; LGKM0; SCHED0; \
  MQ1(0,0); \
  LB32(BUF,1); \
  if (s1) SA1(1-(BUF),1,(T)+1); \
  if (s1) { VM(8); } else { VM(0); } \
  SCHED0; BARR; LGKM0; SCHED0; \
  MQ1(0,1); \
  LA32(BUF,1); \
  if (s2) SA1(BUF,0,(T)+2); \
  SCHED0; BARR; LGKM0; SCHED0; \
  MQ1(1,0); \
  if (s2) SB1(BUF,1,(T)+2); \
  if (s1) { if (s2) { VM(6); } else { VM(2); } } \
  SCHED0; BARR; SCHED0; \
  MQ1(1,1); }

  for (int t2 = 0; t2 < NT; t2 += 2){
    T1(t2, 0);
    T1(t2 + 1, 1);
  }
#undef T1
#undef SA1
#undef SB1
#undef LA32
#undef LB32
#undef MQ1

  SCHED0;
  // epilogue: C/D col = bcol0 + wc*64 + nf*32 + l31; row = mf*64 + wr*32 + (r&3)+8*(r>>2)+4*hi
  #pragma unroll
  for (int mfg = 0; mfg < 4; ++mfg){
    #pragma unroll
    for (int nf = 0; nf < 2; ++nf){
      int cl = bcol0 + wc * 64 + nf * 32 + l31;
      float bv = bias[cl];
      #pragma unroll
      for (int r = 0; r < 16; ++r){
        int rw = arow0 + mfg * 64 + wr * 32 + (r & 3) + 8 * (r >> 2) + 4 * hi;
        float v = acc[mfg][nf][r] + bv;
        Hout[(long)rw * N + cl] = f2bf(gelu_f(v));
      }
    }
  }
}

// ---------------- GEMM2: 256x128, 8 waves 2Mx4N, 32x32x16 MFMA, +bias+resid->f32 ----------------
__global__ __launch_bounds__(512, 2) void gemm2_k(const short* __restrict__ A,
    const short* __restrict__ BT, const float* __restrict__ bias,
    const short* __restrict__ resid, float* __restrict__ Fout, long row0_abs){
  constexpr int K = 4096, NT = 64;
  __shared__ __align__(16) short AsM[2 * 16384];
  __shared__ __align__(16) short BsM[2 * 8192];
  const int tid = threadIdx.x;
  const int lane = tid & 63, wv = tid >> 6;
  const int wr = wv >> 2, wc = wv & 3;          // wave = 128 rows x 32 cols
  const int l31 = lane & 31, hi = lane >> 5;
  int flat = blockIdx.x;
  int xcd = flat & 7, l = flat >> 3;
  int mb = (xcd & 3) * 8 + (l & 7);
  int nb = (xcd >> 2) * 4 + (l >> 3);
  const int arow0 = mb * 256, bcol0 = nb * 128;

  const int r7m = l31 & 7;
  int kof[4];
  #pragma unroll
  for (int ks = 0; ks < 4; ++ks) kof[ks] = ((ks * 2 + hi) ^ r7m) * 8;
  const int aB = (wr * 32 + l31) * 64;
  const int bB = (wc * 32 + l31) * 64;

  const int rr = tid >> 3;
  const int sl8 = ((tid & 7) ^ (rr & 7)) * 8;
  const long aoff = (long)rr * K + sl8;
  const short* Au = A  + (long)arow0 * K;
  const short* Bu = BT + (long)bcol0 * K;
  const int ldsw = wv * 512;

#define SA2(BUF,H,T) { \
  gload16(Au + (long)((H)*128      )*K + (T)*64 + aoff, AsM + (BUF)*16384 + (H)*8192 + ldsw); \
  gload16(Au + (long)((H)*128 + 64 )*K + (T)*64 + aoff, AsM + (BUF)*16384 + (H)*8192 + 4096 + ldsw); }
#define SB2(BUF,H,T) \
  gload16(Bu + (long)((H)*64)*K + (T)*64 + aoff, BsM + (BUF)*8192 + (H)*4096 + ldsw);
#define LA32(BUF,MH) { _Pragma("unroll") for (int mf = 0; mf < 2; ++mf) \
  _Pragma("unroll") for (int ks = 0; ks < 4; ++ks) \
    af[mf][ks] = *(const s16x8*)&AsM[(BUF)*16384 + ((MH)*2+mf)*4096 + aB + kof[ks]]; }
#define LB32(BUF) { _Pragma("unroll") for (int ks = 0; ks < 4; ++ks) \
    bf[ks] = *(const s16x8*)&BsM[(BUF)*8192 + bB + kof[ks]]; }
// MFMA cluster: half MH, k-pair KS2 (4 mfma)
#define MQ2(MH,KS2) { __builtin_amdgcn_s_setprio(1); \
  _Pragma("unroll") for (int mf = 0; mf < 2; ++mf) \
  _Pragma("unroll") for (int kk = 0; kk < 2; ++kk) \
    acc[(MH)*2+mf] = __builtin_amdgcn_mfma_f32_32x32x16_bf16( \
        af[mf][(KS2)*2+kk], bf[(KS2)*2+kk], acc[(MH)*2+mf], 0, 0, 0); \
  __builtin_amdgcn_s_setprio(0); }

  f32x16 acc[4] = {};
  s16x8 af[2][4], bf[4];

  // prologue (r7 ledger): A0h0, B0h1, B0h0, A0h1, A1h0, B1h1 — VM(5)
  SA2(0,0,0); SB2(0,1,0); SB2(0,0,0); SA2(0,1,0); SA2(1,0,1); SB2(1,1,1);
  VM(5); SCHED0; BARR; SCHED0;

#define T2(T, BUF) { const bool s1 = (T)+1 < NT, s2 = (T)+2 < NT; \
  LA32(BUF,0); LB32(BUF); \
  if (s1) SB2(1-(BUF),0,(T)+1); \
  SCHED0; BARR; LGKM0; SCHED0; \
  MQ2(0,0); \
  if (s1) SA2(1-(BUF),1,(T)+1); \
  if (s1) { VM(6); } else { VM(0); } \
  SCHED0; BARR; SCHED0; \
  MQ2(0,1); \
  LA32(BUF,1); \
  if (s2) SA2(BUF,0,(T)+2); \
  SCHED0; BARR; LGKM0; SCHED0; \
  MQ2(1,0); \
  if (s2) SB2(BUF,1,(T)+2); \
  if (s1) { if (s2) { VM(5); } else { VM(2); } } \
  SCHED0; BARR; SCHED0; \
  MQ2(1,1); }

  for (int t2 = 0; t2 < NT; t2 += 2){
    T2(t2, 0);
    T2(t2 + 1, 1);
  }
#undef T2
#undef SA2
#undef SB2
#undef LA32
#undef LB32
#undef MQ2

  SCHED0;
  #pragma unroll
  for (int mfg = 0; mfg < 4; ++mfg){
    int cl = bcol0 + wc * 32 + l31;
    float bv = bias[cl];
    #pragma unroll
    for (int r = 0; r < 16; ++r){
      int rw = arow0 + mfg * 64 + wr * 32 + (r & 3) + 8 * (r >> 2) + 4 * hi;
      float v = acc[mfg][r] + bv;
      float rv = bf2f(resid[(row0_abs + rw) * 1024 + cl]);
      Fout[(row0_abs + rw) * 1024 + cl] = v + rv;
    }
  }
}

// ---------------- LN2 in-place on f32 out ----------------
__global__ __launch_bounds__(256) void ln2_k(float* __restrict__ out,
    const float* __restrict__ g, const float* __restrict__ bb){
  size_t row = blockIdx.x;
  int tid = threadIdx.x;
  float* p = out + row * 1024;
  f32x4 v = *(const f32x4*)(p + tid * 4);
  float sum = v[0] + v[1] + v[2] + v[3];
  float sq  = v[0]*v[0] + v[1]*v[1] + v[2]*v[2] + v[3]*v[3];
  for (int off = 32; off; off >>= 1){ sum += __shfl_down(sum, off); sq += __shfl_down(sq, off); }
  __shared__ float rs[4], rq[4];
  int lane = tid & 63, w = tid >> 6;
  if (lane == 0){ rs[w] = sum; rq[w] = sq; }
  __syncthreads();
  sum = rs[0] + rs[1] + rs[2] + rs[3]; sq = rq[0] + rq[1] + rq[2] + rq[3];
  float mu = sum * (1.0f / 1024.0f);
  float var = sq * (1.0f / 1024.0f) - mu * mu;
  float sc = rsqrtf(var + 1e-5f);
  f32x4 o;
  #pragma unroll
  for (int j = 0; j < 4; ++j){
    int d = tid * 4 + j;
    o[j] = (v[j] - mu) * sc * g[d] + bb[d];
  }
  *(f32x4*)(p + tid * 4) = o;
}

// ---------------- launch ----------------
extern "C" void kernel_launch(void* const* d_in, const int* in_sizes, int n_in,
                              void* d_out, int out_size, void* d_ws, size_t ws_size,
                              hipStream_t stream){
  (void)in_sizes; (void)n_in; (void)out_size; (void)ws_size;
  const int*   tokens = (const int*)d_in[0];
  const float* frw  = (const float*)d_in[1];
  const float* fiw  = (const float*)d_in[2];
  const float* mw   = (const float*)d_in[3];
  const float* po   = (const float*)d_in[4];
  const float* ftew = (const float*)d_in[5];
  const float* fteb = (const float*)d_in[6];
  const float* posph= (const float*)d_in[7];
  const float* awr  = (const float*)d_in[8];
  const float* awi  = (const float*)d_in[9];
  const float* ln1g = (const float*)d_in[10];
  const float* ln1b = (const float*)d_in[11];
  const float* w1   = (const float*)d_in[12];
  const float* b1   = (const float*)d_in[13];
  const float* w2   = (const float*)d_in[14];
  const float* b2   = (const float*)d_in[15];
  const float* ln2g = (const float*)d_in[16];
  const float* ln2b = (const float*)d_in[17];
  float* out = (float*)d_out;

  char* ws = (char*)d_ws;
  size_t o = 0;
  float* residual = (float*)(ws + o); o += (size_t)16384 * 1024 * 4;  // 67.1 MB; later hbuf
  short* xln1     = (short*)(ws + o); o += (size_t)16384 * 1024 * 2;  // 33.6 MB
  short* w1b      = (short*)(ws + o); o += (size_t)4096 * 1024 * 2;
  short* w2b      = (short*)(ws + o); o += (size_t)4096 * 1024 * 2;
  float* ctab     = (float*)(ws + o); o += 524288;
  float* stab     = (float*)(ws + o); o += 524288;
  float* Xr       = (float*)(ws + o); o += 524288;
  float* Xi       = (float*)(ws + o); o += 524288;
  float* Or       = (float*)(ws + o); o += 524288;
  float* Oi       = (float*)(ws + o); o += 524288;
  float* Pr       = (float*)(ws + o); o += (size_t)8 * 4 * 1024 * 32 * 4;
  float* Pi       = (float*)(ws + o); o += (size_t)8 * 4 * 1024 * 32 * 4;
  float* wcs      = (float*)(ws + o); o += 512;
  short* hbuf     = (short*)residual;   // 8192x4096 bf16 aliases dead residual

  prep_wcs_k<<<1, 64, 0, stream>>>(mw, po, wcs);
  prep_tab_k<<<512, 256, 0, stream>>>(ctab, stab);
  transpose_bf16_k<<<dim3(64, 16), 256, 0, stream>>>(w1, w1b, 1024, 4096);
  transpose_bf16_k<<<dim3(16, 64), 256, 0, stream>>>(w2, w2b, 4096, 1024);

  kernelA<<<4096, 256, 0, stream>>>(tokens, frw, fiw, wcs, ftew, fteb, posph, residual);
  kernelB2<<<1024, 256, 0, stream>>>(residual, Pr, Pi);
  reduceB_k<<<512, 256, 0, stream>>>(Pr, Pi, Xr, Xi);
  kernelC<<<256, 128, 0, stream>>>(Xr, Xi, awr, awi, Or, Oi);
  kernelD3<<<2048, 256, 0, stream>>>(Or, Oi, ctab, stab, residual);
  ln1_k<<<16384, 256, 0, stream>>>(residual, ln1g, ln1b, xln1);

  for (int c = 0; c < 2; ++c){
    long row0 = (long)c * 8192;
    gemm1_k<<<512, 512, 0, stream>>>(xln1 + row0 * 1024, w1b, b1, hbuf);
    gemm2_k<<<256, 512, 0, stream>>>(hbuf, w2b, b2, xln1, out, row0);
  }
  ln2_k<<<16384, 256, 0, stream>>>(out, ln2g, ln2b);
}